// Round 9
// baseline (440.979 us; speedup 1.0000x reference)
//
#include <hip/hip_runtime.h>
#include <hip/hip_cooperative_groups.h>

namespace cg = cooperative_groups;

#define Bn 8
#define Ln 256
#define Dn 128
#define Hn 6
#define En 32
#define WXROW (Hn + 2*Dn + En)   // 294
#define ROWS 4

struct P1 {                       // GCN phase scratch (24 KB)
    float adj[ROWS][Ln];          // 4 KB
    float part[8][ROWS][Dn];      // 16 KB
    float t_s[ROWS][Dn];          // 2 KB
    float g_s[ROWS][Dn];          // 2 KB
};
struct P2 {                       // adj phase scratch (~17.8 KB)
    float e_lds[128 * 33];
    float Wa[Hn][Hn];
    float We[Hn][En];
    float bias[Hn];               // Wx_b
};
union SharedU { P1 p1; P2 p2; };

__device__ __forceinline__ void load_wx(const float* __restrict__ Wx_w,
                                        const float* __restrict__ Wx_b,
                                        P2& sp, int t)
{
    if (t < Hn * Hn)
        sp.Wa[t / Hn][t % Hn] = Wx_w[(size_t)(t / Hn) * WXROW + (t % Hn)];
    if (t >= 64 && t < 64 + Hn * En) {
        const int q = t - 64;
        sp.We[q / En][q % En] = Wx_w[(size_t)(q / En) * WXROW + Hn + 2 * Dn + (q % En)];
    }
    if (t >= 32 && t < 32 + Hn)
        sp.bias[t - 32] = Wx_b[t - 32];
    // no barrier here: unit_acc's leading __syncthreads orders these writes
}

// acc[h][kq] = adj_term + e_term + Wx_b for unit (b,i), thread covers
// k = (t>>7)*3 + kq, j = h*128 + (t&127)
__device__ __forceinline__ void unit_acc(
    const float* __restrict__ wadj, const float4 A[4], const float4 Bv[4],
    P2& sp, int b, int i, int t, float acc[2][3])
{
    const int s = t >> 7, jl = t & 127;
    __syncthreads();                  // e_lds free of prior readers; weights ordered
    #pragma unroll
    for (int p = 0; p < 4; ++p) {
        const int idx = t + p * 256;
        const int j = idx >> 3, c = (idx & 7) * 4;
        float* dst = &sp.e_lds[j * 33 + c];
        dst[0] = A[p].x; dst[1] = A[p].y; dst[2] = A[p].z; dst[3] = A[p].w;
    }
    __syncthreads();
    #pragma unroll
    for (int h = 0; h < 2; ++h) {
        const int j = h * 128 + jl;
        float wv[Hn];
        #pragma unroll
        for (int hh = 0; hh < Hn; ++hh)
            wv[hh] = wadj[(((size_t)b * Hn + hh) * Ln + i) * Ln + j];
        const float* ev = &sp.e_lds[jl * 33];
        #pragma unroll
        for (int kq = 0; kq < 3; ++kq) {
            const int k = s * 3 + kq;
            float a = sp.bias[k];
            #pragma unroll
            for (int hh = 0; hh < Hn; ++hh)
                a = fmaf(wv[hh], sp.Wa[k][hh], a);
            #pragma unroll
            for (int c = 0; c < En; ++c)
                a = fmaf(ev[c], sp.We[k][c], a);
            acc[h][kq] = a;
        }
        if (h == 0) {
            __syncthreads();
            #pragma unroll
            for (int p = 0; p < 4; ++p) {
                const int idx = t + p * 256;
                const int j2 = idx >> 3, c = (idx & 7) * 4;
                float* dst = &sp.e_lds[j2 * 33 + c];
                dst[0] = Bv[p].x; dst[1] = Bv[p].y; dst[2] = Bv[p].z; dst[3] = Bv[p].w;
            }
            __syncthreads();
        }
    }
}

__device__ __forceinline__ void unit_store(
    const float* __restrict__ n1_ws, const float* __restrict__ n2_ws,
    float* __restrict__ new_adj, int b, int i, int t, const float acc[2][3])
{
    const int s = t >> 7, jl = t & 127;
    #pragma unroll
    for (int kq = 0; kq < 3; ++kq) {
        const int k = s * 3 + kq;
        const float n1v = n1_ws[((size_t)b * Hn + k) * Ln + i];
        #pragma unroll
        for (int h = 0; h < 2; ++h) {
            const int j = h * 128 + jl;
            const float v = acc[h][kq] + n1v + n2_ws[((size_t)b * Hn + k) * Ln + j];
            new_adj[(((size_t)b * Hn + k) * Ln + i) * Ln + j] = v;
        }
    }
}

// ================= fused cooperative kernel =================
// grid = 1024 blocks x 256 thr; 24 KB LDS, VGPR<=128 -> 4 blocks/CU co-resident
__global__ __launch_bounds__(256, 4) void k_fused(
    const float* __restrict__ x, const float* __restrict__ wadj,
    const float* __restrict__ e,
    const float* __restrict__ W_w, const float* __restrict__ W_b,
    const float* __restrict__ Wx_w, const float* __restrict__ Wx_b,
    const float* __restrict__ Wxx_w, const float* __restrict__ Wxx_b,
    float* __restrict__ out, float* __restrict__ new_adj,
    float* __restrict__ n1_ws, float* __restrict__ n2_ws)
{
    __shared__ SharedU sh;
    const int t = threadIdx.x;
    const int blk = blockIdx.x;

    float acc[2][2][3];

    if (blk >= 512) {
        // ---- pre-sync: stream adj_term + e_term for units 1024..2047 ----
        load_wx(Wx_w, Wx_b, sh.p2, t);
        #pragma unroll
        for (int u = 0; u < 2; ++u) {
            const int idx = blk * 2 + u;
            const int b = idx >> 8, i = idx & 255;
            const float4* ep4 = (const float4*)(e + (((size_t)b * Ln + i) * Ln) * En);
            float4 A[4], Bv[4];
            #pragma unroll
            for (int p = 0; p < 4; ++p) A[p]  = ep4[t + p * 256];
            #pragma unroll
            for (int p = 0; p < 4; ++p) Bv[p] = ep4[1024 + t + p * 256];
            unit_acc(wadj, A, Bv, sh.p2, b, i, t, acc[u]);
        }
    } else {
        // ---- pre-sync: GCN (r4 proven body) ----
        const int b  = blk >> 6;
        const int i0 = (blk & 63) * ROWS;

        // P1: adj[r][j] = mean_h wadj[b,h,i0+r,j]
        {
            const int r = t >> 6, j4 = t & 63;
            const float4* w4 = (const float4*)wadj;
            float4 s4 = {0.f, 0.f, 0.f, 0.f};
            #pragma unroll
            for (int h = 0; h < Hn; ++h) {
                const float4 v = w4[(((size_t)b * Hn + h) * Ln + (i0 + r)) * 64 + j4];
                s4.x += v.x; s4.y += v.y; s4.z += v.z; s4.w += v.w;
            }
            const float inv_h = 1.0f / 6.0f;
            s4.x *= inv_h; s4.y *= inv_h; s4.z *= inv_h; s4.w *= inv_h;
            ((float4*)&sh.p1.adj[0][0])[r * 64 + j4] = s4;
        }
        __syncthreads();

        // P2: part[q][r][d] = sum_{j in slice q} adj[r][j]*x[b,j,d]
        {
            const int q = t >> 5, d4 = t & 31;
            float4 a4[ROWS];
            #pragma unroll
            for (int r = 0; r < ROWS; ++r) a4[r] = {0.f, 0.f, 0.f, 0.f};
            const float4* xp4  = (const float4*)(x + (size_t)b * Ln * Dn) + d4;
            const float4* adj4 = (const float4*)&sh.p1.adj[0][0];
            const int j0 = q * 32;
            #pragma unroll
            for (int jj4 = 0; jj4 < 8; ++jj4) {
                const int j = j0 + jj4 * 4;
                const float4 xv0 = xp4[(size_t)(j + 0) * 32];
                const float4 xv1 = xp4[(size_t)(j + 1) * 32];
                const float4 xv2 = xp4[(size_t)(j + 2) * 32];
                const float4 xv3 = xp4[(size_t)(j + 3) * 32];
                #pragma unroll
                for (int r = 0; r < ROWS; ++r) {
                    const float4 a = adj4[r * 64 + (j >> 2)];
                    float4 v = a4[r];
                    v.x = fmaf(a.x, xv0.x, v.x); v.y = fmaf(a.x, xv0.y, v.y);
                    v.z = fmaf(a.x, xv0.z, v.z); v.w = fmaf(a.x, xv0.w, v.w);
                    v.x = fmaf(a.y, xv1.x, v.x); v.y = fmaf(a.y, xv1.y, v.y);
                    v.z = fmaf(a.y, xv1.z, v.z); v.w = fmaf(a.y, xv1.w, v.w);
                    v.x = fmaf(a.z, xv2.x, v.x); v.y = fmaf(a.z, xv2.y, v.y);
                    v.z = fmaf(a.z, xv2.z, v.z); v.w = fmaf(a.z, xv2.w, v.w);
                    v.x = fmaf(a.w, xv3.x, v.x); v.y = fmaf(a.w, xv3.y, v.y);
                    v.z = fmaf(a.w, xv3.z, v.z); v.w = fmaf(a.w, xv3.w, v.w);
                    a4[r] = v;
                }
            }
            #pragma unroll
            for (int r = 0; r < ROWS; ++r)
                ((float4*)&sh.p1.part[q][r][0])[d4] = a4[r];
        }
        __syncthreads();

        // P3: combine 8 j-slices
        {
            const int dd = t & 127, rr = t >> 7;
            #pragma unroll
            for (int rq = 0; rq < 2; ++rq) {
                const int r = rr + rq * 2;
                float s = 0.f;
                #pragma unroll
                for (int qq = 0; qq < 8; ++qq) s += sh.p1.part[qq][r][dd];
                sh.p1.t_s[r][dd] = s;
            }
        }
        __syncthreads();

        // P4: relu GEMM
        {
            const int ss = t >> 7, dd = t & 127;
            const int r0 = ss, r1 = ss + 2;
            float a0 = W_b[dd], a1 = a0;
            const float4* wr = (const float4*)(W_w + (size_t)dd * Dn);
            const float4* t0 = (const float4*)&sh.p1.t_s[r0][0];
            const float4* t1 = (const float4*)&sh.p1.t_s[r1][0];
            #pragma unroll 8
            for (int c4 = 0; c4 < Dn / 4; ++c4) {
                const float4 w = wr[c4];
                const float4 u0 = t0[c4];
                const float4 u1 = t1[c4];
                a0 = fmaf(u0.x, w.x, a0); a0 = fmaf(u0.y, w.y, a0);
                a0 = fmaf(u0.z, w.z, a0); a0 = fmaf(u0.w, w.w, a0);
                a1 = fmaf(u1.x, w.x, a1); a1 = fmaf(u1.y, w.y, a1);
                a1 = fmaf(u1.z, w.z, a1); a1 = fmaf(u1.w, w.w, a1);
            }
            sh.p1.g_s[r0][dd] = fmaxf(a0, 0.f);
            sh.p1.g_s[r1][dd] = fmaxf(a1, 0.f);
        }
        __syncthreads();

        // P5: out GEMM
        {
            const int ss = t >> 7, dd = t & 127;
            const int r0 = ss, r1 = ss + 2;
            float a0 = Wxx_b[dd], a1 = a0;
            const float4* wr = (const float4*)(Wxx_w + (size_t)dd * Dn);
            const float4* g0 = (const float4*)&sh.p1.g_s[r0][0];
            const float4* g1 = (const float4*)&sh.p1.g_s[r1][0];
            #pragma unroll 8
            for (int c4 = 0; c4 < Dn / 4; ++c4) {
                const float4 w = wr[c4];
                const float4 u0 = g0[c4];
                const float4 u1 = g1[c4];
                a0 = fmaf(u0.x, w.x, a0); a0 = fmaf(u0.y, w.y, a0);
                a0 = fmaf(u0.z, w.z, a0); a0 = fmaf(u0.w, w.w, a0);
                a1 = fmaf(u1.x, w.x, a1); a1 = fmaf(u1.y, w.y, a1);
                a1 = fmaf(u1.z, w.z, a1); a1 = fmaf(u1.w, w.w, a1);
            }
            out[((size_t)b * Ln + (i0 + r0)) * Dn + dd] = a0;
            out[((size_t)b * Ln + (i0 + r1)) * Dn + dd] = a1;
        }

        // P6: n1/n2 (g_s stable since P4 barrier)
        if (t < ROWS * 2 * Hn) {
            const int r  = t / (2 * Hn);
            const int kk = t % (2 * Hn);
            const int k  = (kk < Hn) ? kk : (kk - Hn);
            const bool isn2 = (kk >= Hn);
            const float* wrow = Wx_w + (size_t)k * WXROW + Hn + (isn2 ? Dn : 0);
            float a = 0.f;
            #pragma unroll 8
            for (int c = 0; c < Dn; ++c)
                a = fmaf(sh.p1.g_s[r][c], wrow[c], a);
            const size_t widx = ((size_t)b * Hn + k) * Ln + (i0 + r);
            if (isn2) n2_ws[widx] = a;
            else      n1_ws[widx] = a;
        }
        __threadfence();   // make n1/n2 globally visible before grid sync
    }

    cg::this_grid().sync();

    if (blk >= 512) {
        // ---- post-sync: finalize pre-computed units ----
        #pragma unroll
        for (int u = 0; u < 2; ++u) {
            const int idx = blk * 2 + u;
            unit_store(n1_ws, n2_ws, new_adj, idx >> 8, idx & 255, t, acc[u]);
        }
    } else {
        // ---- post-sync: GCN blocks process units 0..1023 cold ----
        load_wx(Wx_w, Wx_b, sh.p2, t);
        #pragma unroll
        for (int u = 0; u < 2; ++u) {
            const int idx = blk * 2 + u;
            const int b = idx >> 8, i = idx & 255;
            const float4* ep4 = (const float4*)(e + (((size_t)b * Ln + i) * Ln) * En);
            float4 A[4], Bv[4];
            #pragma unroll
            for (int p = 0; p < 4; ++p) A[p]  = ep4[t + p * 256];
            #pragma unroll
            for (int p = 0; p < 4; ++p) Bv[p] = ep4[1024 + t + p * 256];
            unit_acc(wadj, A, Bv, sh.p2, b, i, t, acc[u]);
            unit_store(n1_ws, n2_ws, new_adj, b, i, t, acc[u]);
        }
    }
}

// ================= fallback path (r4 two-kernel, proven 146 µs) =================
__global__ __launch_bounds__(256) void k_gcn_fb(
    const float* __restrict__ x, const float* __restrict__ wadj,
    const float* __restrict__ W_w, const float* __restrict__ W_b,
    const float* __restrict__ Wx_w,
    const float* __restrict__ Wxx_w, const float* __restrict__ Wxx_b,
    float* __restrict__ out, float* __restrict__ n1_ws, float* __restrict__ n2_ws)
{
    __shared__ P1 sp;
    const int t  = threadIdx.x;
    const int b  = blockIdx.x >> 6;
    const int i0 = (blockIdx.x & 63) * ROWS;
    {
        const int r = t >> 6, j4 = t & 63;
        const float4* w4 = (const float4*)wadj;
        float4 s4 = {0.f, 0.f, 0.f, 0.f};
        #pragma unroll
        for (int h = 0; h < Hn; ++h) {
            const float4 v = w4[(((size_t)b * Hn + h) * Ln + (i0 + r)) * 64 + j4];
            s4.x += v.x; s4.y += v.y; s4.z += v.z; s4.w += v.w;
        }
        const float inv_h = 1.0f / 6.0f;
        s4.x *= inv_h; s4.y *= inv_h; s4.z *= inv_h; s4.w *= inv_h;
        ((float4*)&sp.adj[0][0])[r * 64 + j4] = s4;
    }
    __syncthreads();
    {
        const int q = t >> 5, d4 = t & 31;
        float4 a4[ROWS];
        #pragma unroll
        for (int r = 0; r < ROWS; ++r) a4[r] = {0.f, 0.f, 0.f, 0.f};
        const float4* xp4  = (const float4*)(x + (size_t)b * Ln * Dn) + d4;
        const float4* adj4 = (const float4*)&sp.adj[0][0];
        const int j0 = q * 32;
        #pragma unroll
        for (int jj4 = 0; jj4 < 8; ++jj4) {
            const int j = j0 + jj4 * 4;
            const float4 xv0 = xp4[(size_t)(j + 0) * 32];
            const float4 xv1 = xp4[(size_t)(j + 1) * 32];
            const float4 xv2 = xp4[(size_t)(j + 2) * 32];
            const float4 xv3 = xp4[(size_t)(j + 3) * 32];
            #pragma unroll
            for (int r = 0; r < ROWS; ++r) {
                const float4 a = adj4[r * 64 + (j >> 2)];
                float4 v = a4[r];
                v.x = fmaf(a.x, xv0.x, v.x); v.y = fmaf(a.x, xv0.y, v.y);
                v.z = fmaf(a.x, xv0.z, v.z); v.w = fmaf(a.x, xv0.w, v.w);
                v.x = fmaf(a.y, xv1.x, v.x); v.y = fmaf(a.y, xv1.y, v.y);
                v.z = fmaf(a.y, xv1.z, v.z); v.w = fmaf(a.y, xv1.w, v.w);
                v.x = fmaf(a.z, xv2.x, v.x); v.y = fmaf(a.z, xv2.y, v.y);
                v.z = fmaf(a.z, xv2.z, v.z); v.w = fmaf(a.z, xv2.w, v.w);
                v.x = fmaf(a.w, xv3.x, v.x); v.y = fmaf(a.w, xv3.y, v.y);
                v.z = fmaf(a.w, xv3.z, v.z); v.w = fmaf(a.w, xv3.w, v.w);
                a4[r] = v;
            }
        }
        #pragma unroll
        for (int r = 0; r < ROWS; ++r)
            ((float4*)&sp.part[q][r][0])[d4] = a4[r];
    }
    __syncthreads();
    {
        const int dd = t & 127, rr = t >> 7;
        #pragma unroll
        for (int rq = 0; rq < 2; ++rq) {
            const int r = rr + rq * 2;
            float s = 0.f;
            #pragma unroll
            for (int qq = 0; qq < 8; ++qq) s += sp.part[qq][r][dd];
            sp.t_s[r][dd] = s;
        }
    }
    __syncthreads();
    {
        const int ss = t >> 7, dd = t & 127;
        const int r0 = ss, r1 = ss + 2;
        float a0 = W_b[dd], a1 = a0;
        const float4* wr = (const float4*)(W_w + (size_t)dd * Dn);
        const float4* t0 = (const float4*)&sp.t_s[r0][0];
        const float4* t1 = (const float4*)&sp.t_s[r1][0];
        #pragma unroll 8
        for (int c4 = 0; c4 < Dn / 4; ++c4) {
            const float4 w = wr[c4];
            const float4 u0 = t0[c4];
            const float4 u1 = t1[c4];
            a0 = fmaf(u0.x, w.x, a0); a0 = fmaf(u0.y, w.y, a0);
            a0 = fmaf(u0.z, w.z, a0); a0 = fmaf(u0.w, w.w, a0);
            a1 = fmaf(u1.x, w.x, a1); a1 = fmaf(u1.y, w.y, a1);
            a1 = fmaf(u1.z, w.z, a1); a1 = fmaf(u1.w, w.w, a1);
        }
        sp.g_s[r0][dd] = fmaxf(a0, 0.f);
        sp.g_s[r1][dd] = fmaxf(a1, 0.f);
    }
    __syncthreads();
    {
        const int ss = t >> 7, dd = t & 127;
        const int r0 = ss, r1 = ss + 2;
        float a0 = Wxx_b[dd], a1 = a0;
        const float4* wr = (const float4*)(Wxx_w + (size_t)dd * Dn);
        const float4* g0 = (const float4*)&sp.g_s[r0][0];
        const float4* g1 = (const float4*)&sp.g_s[r1][0];
        #pragma unroll 8
        for (int c4 = 0; c4 < Dn / 4; ++c4) {
            const float4 w = wr[c4];
            const float4 u0 = g0[c4];
            const float4 u1 = g1[c4];
            a0 = fmaf(u0.x, w.x, a0); a0 = fmaf(u0.y, w.y, a0);
            a0 = fmaf(u0.z, w.z, a0); a0 = fmaf(u0.w, w.w, a0);
            a1 = fmaf(u1.x, w.x, a1); a1 = fmaf(u1.y, w.y, a1);
            a1 = fmaf(u1.z, w.z, a1); a1 = fmaf(u1.w, w.w, a1);
        }
        out[((size_t)b * Ln + (i0 + r0)) * Dn + dd] = a0;
        out[((size_t)b * Ln + (i0 + r1)) * Dn + dd] = a1;
    }
    if (t < ROWS * 2 * Hn) {
        const int r  = t / (2 * Hn);
        const int kk = t % (2 * Hn);
        const int k  = (kk < Hn) ? kk : (kk - Hn);
        const bool isn2 = (kk >= Hn);
        const float* wrow = Wx_w + (size_t)k * WXROW + Hn + (isn2 ? Dn : 0);
        float a = 0.f;
        #pragma unroll 8
        for (int c = 0; c < Dn; ++c)
            a = fmaf(sp.g_s[r][c], wrow[c], a);
        const size_t widx = ((size_t)b * Hn + k) * Ln + (i0 + r);
        if (isn2) n2_ws[widx] = a;
        else      n1_ws[widx] = a;
    }
}

__global__ __launch_bounds__(256) void k_adj_fb(
    const float* __restrict__ wadj, const float* __restrict__ e,
    const float* __restrict__ Wx_w, const float* __restrict__ Wx_b,
    const float* __restrict__ n1_ws, const float* __restrict__ n2_ws,
    float* __restrict__ new_adj)
{
    __shared__ P2 sp;
    const int t = threadIdx.x;
    const int b = blockIdx.x >> 8;
    const int i = blockIdx.x & 255;
    load_wx(Wx_w, Wx_b, sp, t);
    const float4* ep4 = (const float4*)(e + (((size_t)b * Ln + i) * Ln) * En);
    float4 A[4], Bv[4];
    #pragma unroll
    for (int p = 0; p < 4; ++p) A[p]  = ep4[t + p * 256];
    #pragma unroll
    for (int p = 0; p < 4; ++p) Bv[p] = ep4[1024 + t + p * 256];
    float acc[2][3];
    unit_acc(wadj, A, Bv, sp, b, i, t, acc);
    unit_store(n1_ws, n2_ws, new_adj, b, i, t, acc);
}

extern "C" void kernel_launch(void* const* d_in, const int* in_sizes, int n_in,
                              void* d_out, int out_size, void* d_ws, size_t ws_size,
                              hipStream_t stream) {
    const float* x      = (const float*)d_in[0];
    const float* wadj   = (const float*)d_in[1];
    const float* e      = (const float*)d_in[2];
    const float* W_w    = (const float*)d_in[3];
    const float* W_b    = (const float*)d_in[4];
    const float* Wx_w   = (const float*)d_in[5];
    const float* Wx_b   = (const float*)d_in[6];
    const float* Wxx_w  = (const float*)d_in[7];
    const float* Wxx_b  = (const float*)d_in[8];

    float* out      = (float*)d_out;                   // (B,L,D)
    float* new_adj  = out + (size_t)Bn * Ln * Dn;      // (B,H,L,L)

    float* n1_ws = (float*)d_ws;                       // (B,H,L)
    float* n2_ws = n1_ws + (size_t)Bn * Hn * Ln;       // (B,H,L)

    void* args[] = {
        (void*)&x, (void*)&wadj, (void*)&e, (void*)&W_w, (void*)&W_b,
        (void*)&Wx_w, (void*)&Wx_b, (void*)&Wxx_w, (void*)&Wxx_b,
        (void*)&out, (void*)&new_adj, (void*)&n1_ws, (void*)&n2_ws
    };
    const hipError_t err = hipLaunchCooperativeKernel(
        reinterpret_cast<void*>(k_fused), dim3(1024), dim3(256), args, 0, stream);
    if (err != hipSuccess) {
        // deterministic fallback: proven two-kernel path
        k_gcn_fb<<<Bn * (Ln / ROWS), 256, 0, stream>>>(
            x, wadj, W_w, W_b, Wx_w, Wxx_w, Wxx_b, out, n1_ws, n2_ws);
        k_adj_fb<<<Bn * Ln, 256, 0, stream>>>(
            wadj, e, Wx_w, Wx_b, n1_ws, n2_ws, new_adj);
    }
}